// Round 1
// baseline (2676.989 us; speedup 1.0000x reference)
//
#include <hip/hip_runtime.h>
#include <hip/hip_bf16.h>

typedef __attribute__((ext_vector_type(8))) short bf16x8;
typedef __attribute__((ext_vector_type(4))) float f32x4;
typedef __attribute__((ext_vector_type(4))) int int4v;

#define LB __launch_bounds__(256)

__device__ __forceinline__ unsigned short f2b(float f) {
  __hip_bfloat16 h = __float2bfloat16(f);
  return __builtin_bit_cast(unsigned short, h);
}
__device__ __forceinline__ float b2f(unsigned short u) {
  __hip_bfloat16 h = __builtin_bit_cast(__hip_bfloat16, u);
  return __bfloat162float(h);
}

// ---------------- embed: x[b,t,:] = tok_emb[idx[b,t],:] + pos_emb[t,:] ----------------
__global__ LB void embed_kernel(const int* __restrict__ idx, const float* __restrict__ tok,
                                const float* __restrict__ pos, float* __restrict__ X) {
  const int m = blockIdx.x;          // 0..2047 = b*1024+t
  const int t = m & 1023;
  const int token = idx[m];
  const int c = threadIdx.x * 4;
  const float4 a = *(const float4*)(tok + (size_t)token * 1024 + c);
  const float4 p = *(const float4*)(pos + (size_t)t * 1024 + c);
  float4 o; o.x = a.x + p.x; o.y = a.y + p.y; o.z = a.z + p.z; o.w = a.w + p.w;
  *(float4*)(X + (size_t)m * 1024 + c) = o;
}

// ---------------- layernorm over E=1024, writes f32 (opt) + bf16 ----------------
template<bool WF32>
__global__ LB void ln_kernel(const float* __restrict__ X, const float* __restrict__ W,
                             float* __restrict__ Yf, unsigned short* __restrict__ Yb) {
  const int row = blockIdx.x;
  const float* xr = X + (size_t)row * 1024;
  const int c = threadIdx.x * 4;
  const float4 v = *(const float4*)(xr + c);
  float s = v.x + v.y + v.z + v.w;
  float q = v.x*v.x + v.y*v.y + v.z*v.z + v.w*v.w;
  #pragma unroll
  for (int d = 32; d > 0; d >>= 1) { s += __shfl_down(s, d); q += __shfl_down(q, d); }
  __shared__ float ss[4], sq[4];
  const int wid = threadIdx.x >> 6;
  if ((threadIdx.x & 63) == 0) { ss[wid] = s; sq[wid] = q; }
  __syncthreads();
  const float fs = ss[0] + ss[1] + ss[2] + ss[3];
  const float fq = sq[0] + sq[1] + sq[2] + sq[3];
  const float mean = fs * (1.0f / 1024.0f);
  const float var = fq * (1.0f / 1024.0f) - mean * mean;
  const float rstd = rsqrtf(var + 1e-5f);
  const float4 w = *(const float4*)(W + c);
  float4 o;
  o.x = (v.x - mean) * rstd * w.x; o.y = (v.y - mean) * rstd * w.y;
  o.z = (v.z - mean) * rstd * w.z; o.w = (v.w - mean) * rstd * w.w;
  if (WF32) *(float4*)(Yf + (size_t)row * 1024 + c) = o;
  unsigned long long pk = (unsigned long long)f2b(o.x)
      | ((unsigned long long)f2b(o.y) << 16)
      | ((unsigned long long)f2b(o.z) << 32)
      | ((unsigned long long)f2b(o.w) << 48);
  *(unsigned long long*)(Yb + (size_t)row * 1024 + c) = pk;
}

// ---------------- generic weight transpose+convert: dst[rowOff+c][r] = bf16(src[r][c]) ----------------
__global__ LB void transpose_w(const float* __restrict__ src, long long srcZ,
                               unsigned short* __restrict__ dst, long long dstZ,
                               int R, int C, int rowOff, int ldDst) {
  __shared__ float tile[32][33];
  const int z = blockIdx.z;
  const float* S = src + (size_t)z * srcZ;
  unsigned short* D = dst + (size_t)z * dstZ;
  const int c0 = blockIdx.x * 32, r0 = blockIdx.y * 32;
  const int tx = threadIdx.x & 31, ty = threadIdx.x >> 5;   // 32 x 8
  #pragma unroll
  for (int u = 0; u < 4; ++u)
    tile[ty + u * 8][tx] = S[(size_t)(r0 + ty + u * 8) * C + c0 + tx];
  __syncthreads();
  #pragma unroll
  for (int u = 0; u < 4; ++u)
    D[(size_t)(rowOff + c0 + ty + u * 8) * ldDst + r0 + tx] = f2b(tile[tx][ty + u * 8]);
}

// ---------------- v transpose: vT[b][n*64+d][t] = qkvb[b*1024+t][1280+n*64+d] ----------------
__global__ LB void transpose_v(const unsigned short* __restrict__ src, unsigned short* __restrict__ dst) {
  __shared__ unsigned short tile[32][33];
  const int b = blockIdx.z;
  const int c0 = blockIdx.x * 32, t0 = blockIdx.y * 32;
  const int tx = threadIdx.x & 31, ty = threadIdx.x >> 5;
  #pragma unroll
  for (int u = 0; u < 4; ++u)
    tile[ty + u * 8][tx] = src[(size_t)(b * 1024 + t0 + ty + u * 8) * 1536 + 1280 + c0 + tx];
  __syncthreads();
  #pragma unroll
  for (int u = 0; u < 4; ++u)
    dst[((size_t)b * 256 + c0 + ty + u * 8) * 1024 + t0 + tx] = tile[tx][ty + u * 8];
}

// ---------------- causal softmax over bf16 scores, in place, scale 1/8 ----------------
__global__ LB void softmax_causal(unsigned short* __restrict__ P) {
  const int i = blockIdx.x;       // query row
  const int head = blockIdx.y;    // 0..31
  unsigned short* row = P + ((size_t)head * 1024 + i) * 1024;
  const int tid = threadIdx.x;
  float sv[4];
  float mx = -1e30f;
  #pragma unroll
  for (int u = 0; u < 4; ++u) {
    const int j = tid + u * 256;
    const float s = (j <= i) ? b2f(row[j]) * 0.125f : -1e30f;
    sv[u] = s;
    mx = fmaxf(mx, s);
  }
  #pragma unroll
  for (int d = 32; d > 0; d >>= 1) mx = fmaxf(mx, __shfl_down(mx, d));
  __shared__ float sm[4];
  if ((tid & 63) == 0) sm[tid >> 6] = mx;
  __syncthreads();
  mx = fmaxf(fmaxf(sm[0], sm[1]), fmaxf(sm[2], sm[3]));
  float se = 0.0f;
  #pragma unroll
  for (int u = 0; u < 4; ++u) {
    const int j = tid + u * 256;
    const float e = (j <= i) ? __expf(sv[u] - mx) : 0.0f;
    sv[u] = e; se += e;
  }
  #pragma unroll
  for (int d = 32; d > 0; d >>= 1) se += __shfl_down(se, d);
  __shared__ float ssum[4];
  if ((tid & 63) == 0) ssum[tid >> 6] = se;
  __syncthreads();
  se = ssum[0] + ssum[1] + ssum[2] + ssum[3];
  const float inv = 1.0f / se;
  #pragma unroll
  for (int u = 0; u < 4; ++u) {
    const int j = tid + u * 256;
    row[j] = f2b(sv[u] * inv);
  }
}

// ---------------- NT GEMM: C[M,N] = A[M,K] * Bt[N,K]^T, bf16 in, f32 acc ----------------
// ATTN: 0 = linear batch strides, 1 = QK^T head mode, 2 = PV head mode
template<int BM, int BN, bool BF16OUT, bool RELU, bool RESID, int ATTN, bool CAUSAL, bool KC>
__global__ LB void gemm_nt(const unsigned short* __restrict__ A, const unsigned short* __restrict__ Bt,
                           void* __restrict__ Cv, const float* __restrict__ Res,
                           int M, int N, int K, int lda, int ldb, int ldc,
                           long long sA, long long sB, long long sC) {
  (void)M; (void)N;
  constexpr int BK = 32;
  constexpr int WM = BM / 2, WN = BN / 2;     // 2x2 wave grid
  constexpr int FM = WM / 16, FN = WN / 16;
  constexpr int LP = 40;                      // padded LDS row (ushorts): 80B, 16B-aligned, 2-way bank alias only
  const int bx = blockIdx.x, by = blockIdx.y, bz = blockIdx.z;
  if (CAUSAL && bx > by) return;

  long long aoff, boff, coff;
  if (ATTN == 1) {
    const int b = bz >> 4, hh = bz & 15, n = hh & 3;
    aoff = (long long)b * sA + hh * 64;           // Q[b, t, hh*64+d]
    boff = (long long)b * sB + 1024 + n * 64;     // K[b, t', 1024+n*64+d]
    coff = (long long)bz * sC;                    // scores[bz, t, t']
  } else if (ATTN == 2) {
    const int b = bz >> 4, hh = bz & 15, n = hh & 3;
    aoff = (long long)bz * sA;                    // probs[bz, t, t']
    boff = (long long)(b * 4 + n) * sB;           // vT[b, n, d, t']
    coff = (long long)b * sC + hh * 64;           // o[b, t, hh*64+d]
  } else {
    aoff = (long long)bz * sA; boff = (long long)bz * sB; coff = (long long)bz * sC;
  }
  const unsigned short* Ab = A + aoff;
  const unsigned short* Bb = Bt + boff;

  const int tid = threadIdx.x;
  const int lane = tid & 63, wid = tid >> 6;
  const int wr = wid >> 1, wc = wid & 1;

  __shared__ unsigned short lsA[BM * LP];
  __shared__ unsigned short lsB[BN * LP];

  f32x4 acc[FM][FN] = {};

  constexpr int TPRA = 256 / BM, CHA = BK / TPRA;   // threads/row, ushorts/thread
  constexpr int TPRB = 256 / BN, CHB = BK / TPRB;
  const int ra = tid / TPRA, ka = (tid % TPRA) * CHA;
  const int rb = tid / TPRB, kb = (tid % TPRB) * CHB;
  const int m0 = by * BM, n0 = bx * BN;

  const int Kend = KC ? (m0 + BM < K ? m0 + BM : K) : K;   // causal PV: P[t,k]=0 for k>t

  for (int k0 = 0; k0 < Kend; k0 += BK) {
    int4v ta[CHA / 8], tb[CHB / 8];
    const int4v* ga = (const int4v*)(Ab + (size_t)(m0 + ra) * lda + k0 + ka);
    #pragma unroll
    for (int i = 0; i < CHA / 8; ++i) ta[i] = ga[i];
    const int4v* gb = (const int4v*)(Bb + (size_t)(n0 + rb) * ldb + k0 + kb);
    #pragma unroll
    for (int i = 0; i < CHB / 8; ++i) tb[i] = gb[i];
    __syncthreads();
    #pragma unroll
    for (int i = 0; i < CHA / 8; ++i) *(int4v*)&lsA[ra * LP + ka + i * 8] = ta[i];
    #pragma unroll
    for (int i = 0; i < CHB / 8; ++i) *(int4v*)&lsB[rb * LP + kb + i * 8] = tb[i];
    __syncthreads();

    const int kk = (lane >> 4) * 8;
    bf16x8 af[FM], bfv[FN];
    #pragma unroll
    for (int mi = 0; mi < FM; ++mi)
      af[mi] = *(const bf16x8*)&lsA[(wr * WM + mi * 16 + (lane & 15)) * LP + kk];
    #pragma unroll
    for (int nj = 0; nj < FN; ++nj)
      bfv[nj] = *(const bf16x8*)&lsB[(wc * WN + nj * 16 + (lane & 15)) * LP + kk];
    #pragma unroll
    for (int mi = 0; mi < FM; ++mi)
      #pragma unroll
      for (int nj = 0; nj < FN; ++nj)
        acc[mi][nj] = __builtin_amdgcn_mfma_f32_16x16x32_bf16(af[mi], bfv[nj], acc[mi][nj], 0, 0, 0);
  }

  // epilogue: C/D layout col=lane&15, row=(lane>>4)*4+reg  [m89-verified]
  const int r0 = (lane >> 4) * 4, c0 = lane & 15;
  #pragma unroll
  for (int mi = 0; mi < FM; ++mi) {
    #pragma unroll
    for (int nj = 0; nj < FN; ++nj) {
      const int c = n0 + wc * WN + nj * 16 + c0;
      #pragma unroll
      for (int j = 0; j < 4; ++j) {
        const int r = m0 + wr * WM + mi * 16 + r0 + j;
        float v = acc[mi][nj][j];
        if (RELU) v = fmaxf(v, 0.0f);
        if (RESID) v += Res[(size_t)r * ldc + c];
        const size_t o = (size_t)coff + (size_t)r * ldc + c;
        if (BF16OUT) ((unsigned short*)Cv)[o] = f2b(v);
        else ((float*)Cv)[o] = v;
      }
    }
  }
}

extern "C" void kernel_launch(void* const* d_in, const int* in_sizes, int n_in,
                              void* d_out, int out_size, void* d_ws, size_t ws_size,
                              hipStream_t stream) {
  (void)in_sizes; (void)n_in; (void)out_size;
  const int*   idx      = (const int*)d_in[0];
  const float* tok_emb  = (const float*)d_in[1];
  const float* pos_emb  = (const float*)d_in[2];
  const float* q_proj   = (const float*)d_in[3];
  const float* kv_proj  = (const float*)d_in[4];
  const float* out_proj = (const float*)d_in[5];
  const float* fc_in    = (const float*)d_in[6];
  const float* fc_out   = (const float*)d_in[7];
  const float* scale    = (const float*)d_in[8];
  const float* out_scl  = (const float*)d_in[9];
  const float* lm_head  = (const float*)d_in[10];
  float* out = (float*)d_out;

  char* ws = (char*)d_ws;
  size_t off = 0;
  auto alloc = [&](size_t bytes) -> void* {
    void* p = ws + off;
    off += (bytes + 255) & ~(size_t)255;
    return p;
  };
  // per-layer transposed bf16 weights (reused each layer)
  unsigned short* WqkvT = (unsigned short*)alloc((size_t)1536 * 1024 * 2); // rows: q 0..1023, k 1024..1279, v 1280..1535
  unsigned short* WoT   = (unsigned short*)alloc((size_t)1024 * 1024 * 2);
  unsigned short* F1T   = (unsigned short*)alloc((size_t)4096 * 1024 * 2);
  unsigned short* F2T   = (unsigned short*)alloc((size_t)1024 * 4096 * 2);
  // activations
  float*  xbuf  = (float*)alloc((size_t)2048 * 1024 * 4);   // residual stream
  float*  hbuf  = (float*)alloc((size_t)2048 * 1024 * 4);   // ln1 out (f32)
  float*  h2buf = (float*)alloc((size_t)2048 * 1024 * 4);   // ln2 out (f32)
  unsigned short* actb  = (unsigned short*)alloc((size_t)2048 * 1024 * 2); // bf16 ln out (reused)
  unsigned short* qkvb  = (unsigned short*)alloc((size_t)2048 * 1536 * 2); // [b,t, q|k|v]
  unsigned short* vT    = (unsigned short*)alloc((size_t)2 * 256 * 1024 * 2); // [b,n,d,t]
  unsigned short* probs = (unsigned short*)alloc((size_t)32 * 1024 * 1024 * 2); // scores/probs; reused for LmT at end
  unsigned short* ob    = (unsigned short*)alloc((size_t)2048 * 1024 * 2); // attention output
  unsigned short* m1    = (unsigned short*)alloc((size_t)2048 * 4096 * 2); // mlp hidden
  if (off > ws_size) return;  // workspace too small -> visible failure, no corruption

  const dim3 thr(256);

  embed_kernel<<<dim3(2048), thr, 0, stream>>>(idx, tok_emb, pos_emb, xbuf);

  for (int l = 0; l < 8; ++l) {
    // weight prep for this layer
    transpose_w<<<dim3(32, 32, 1), thr, 0, stream>>>(q_proj + (size_t)l * 1024 * 1024, 0, WqkvT, 0, 1024, 1024, 0, 1024);
    transpose_w<<<dim3(8, 32, 1), thr, 0, stream>>>(kv_proj + (size_t)l * 2 * 1024 * 256, 0, WqkvT, 0, 1024, 256, 1024, 1024);
    transpose_w<<<dim3(8, 32, 1), thr, 0, stream>>>(kv_proj + (size_t)l * 2 * 1024 * 256 + 1024 * 256, 0, WqkvT, 0, 1024, 256, 1280, 1024);
    transpose_w<<<dim3(32, 32, 1), thr, 0, stream>>>(out_proj + (size_t)l * 1024 * 1024, 0, WoT, 0, 1024, 1024, 0, 1024);
    transpose_w<<<dim3(128, 32, 1), thr, 0, stream>>>(fc_in + (size_t)l * 1024 * 4096, 0, F1T, 0, 1024, 4096, 0, 1024);
    transpose_w<<<dim3(32, 128, 1), thr, 0, stream>>>(fc_out + (size_t)l * 4096 * 1024, 0, F2T, 0, 4096, 1024, 0, 4096);

    const float* w1 = scale + (size_t)l * 2048;
    const float* w2 = w1 + 1024;

    // h = ln1(x)
    ln_kernel<true><<<dim3(2048), thr, 0, stream>>>(xbuf, w1, hbuf, actb);
    // qkv = h @ Wqkv   [2048,1536]
    gemm_nt<128, 128, true, false, false, 0, false, false><<<dim3(12, 16, 1), thr, 0, stream>>>(
        actb, WqkvT, qkvb, nullptr, 2048, 1536, 1024, 1024, 1024, 1536, 0, 0, 0);
    // vT[b,n,d,t]
    transpose_v<<<dim3(8, 32, 2), thr, 0, stream>>>(qkvb, vT);
    // scores = Q K^T  (causal tile skip), bf16 out
    gemm_nt<128, 128, true, false, false, 1, true, false><<<dim3(8, 8, 32), thr, 0, stream>>>(
        qkvb, qkvb, probs, nullptr, 1024, 1024, 64, 1536, 1536, 1024,
        1536LL * 1024, 1536LL * 1024, 1024LL * 1024);
    // softmax with 1/sqrt(64) scale + causal mask, in place
    softmax_causal<<<dim3(1024, 32), thr, 0, stream>>>(probs);
    // o = P @ V   (K-loop truncated at causal boundary)
    gemm_nt<128, 64, true, false, false, 2, false, true><<<dim3(1, 8, 32), thr, 0, stream>>>(
        probs, vT, ob, nullptr, 1024, 64, 1024, 1024, 1024, 1024,
        1024LL * 1024, 64LL * 1024, 1024LL * 1024);
    // x = h + o @ Wo   (f32 residual)
    gemm_nt<128, 128, false, false, true, 0, false, false><<<dim3(8, 16, 1), thr, 0, stream>>>(
        ob, WoT, xbuf, hbuf, 2048, 1024, 1024, 1024, 1024, 1024, 0, 0, 0);
    // h2 = ln2(x)
    ln_kernel<true><<<dim3(2048), thr, 0, stream>>>(xbuf, w2, h2buf, actb);
    // m1 = relu(h2 @ fc1)
    gemm_nt<128, 128, true, true, false, 0, false, false><<<dim3(32, 16, 1), thr, 0, stream>>>(
        actb, F1T, m1, nullptr, 2048, 4096, 1024, 1024, 1024, 4096, 0, 0, 0);
    // x = h2 + m1 @ fc2
    gemm_nt<128, 128, false, false, true, 0, false, false><<<dim3(8, 16, 1), thr, 0, stream>>>(
        m1, F2T, xbuf, h2buf, 2048, 1024, 4096, 4096, 4096, 1024, 0, 0, 0);
  }

  // lm_head transpose reuses the (now dead) probs buffer: 65.5 MB <= 67.1 MB
  unsigned short* LmT = probs;
  transpose_w<<<dim3(1000, 32, 1), thr, 0, stream>>>(lm_head, 0, LmT, 0, 1024, 32000, 0, 1024);
  // final ln (bf16 out only)
  ln_kernel<false><<<dim3(2048), thr, 0, stream>>>(xbuf, out_scl, nullptr, actb);
  // logits = x @ lm_head  -> f32 d_out
  gemm_nt<128, 128, false, false, false, 0, false, false><<<dim3(250, 16, 1), thr, 0, stream>>>(
      actb, LmT, out, nullptr, 2048, 32000, 1024, 1024, 1024, 32000, 0, 0, 0);
}

// Round 2
// 2440.814 us; speedup vs baseline: 1.0968x; 1.0968x over previous
//
#include <hip/hip_runtime.h>
#include <hip/hip_bf16.h>

typedef __attribute__((ext_vector_type(8))) short bf16x8;
typedef __attribute__((ext_vector_type(4))) float f32x4;

#define LB __launch_bounds__(256)

__device__ __forceinline__ unsigned short f2b(float f) {
  __hip_bfloat16 h = __float2bfloat16(f);
  return __builtin_bit_cast(unsigned short, h);
}
__device__ __forceinline__ float b2f(unsigned short u) {
  __hip_bfloat16 h = __builtin_bit_cast(__hip_bfloat16, u);
  return __bfloat162float(h);
}

// async global->LDS, 16B per lane. LDS dest must be wave-uniform base + lane*16.
#define GLDS(gp, lp)                                                        \
  __builtin_amdgcn_global_load_lds(                                         \
      (const __attribute__((address_space(1))) void*)(gp),                  \
      (__attribute__((address_space(3))) void*)(lp), 16, 0, 0)

// ---------------- embed ----------------
__global__ LB void embed_kernel(const int* __restrict__ idx, const float* __restrict__ tok,
                                const float* __restrict__ pos, float* __restrict__ X) {
  const int m = blockIdx.x;
  const int t = m & 1023;
  const int token = idx[m];
  const int c = threadIdx.x * 4;
  const float4 a = *(const float4*)(tok + (size_t)token * 1024 + c);
  const float4 p = *(const float4*)(pos + (size_t)t * 1024 + c);
  float4 o; o.x = a.x + p.x; o.y = a.y + p.y; o.z = a.z + p.z; o.w = a.w + p.w;
  *(float4*)(X + (size_t)m * 1024 + c) = o;
}

// ---------------- layernorm ----------------
template<bool WF32>
__global__ LB void ln_kernel(const float* __restrict__ X, const float* __restrict__ W,
                             float* __restrict__ Yf, unsigned short* __restrict__ Yb) {
  const int row = blockIdx.x;
  const float* xr = X + (size_t)row * 1024;
  const int c = threadIdx.x * 4;
  const float4 v = *(const float4*)(xr + c);
  float s = v.x + v.y + v.z + v.w;
  float q = v.x*v.x + v.y*v.y + v.z*v.z + v.w*v.w;
  #pragma unroll
  for (int d = 32; d > 0; d >>= 1) { s += __shfl_down(s, d); q += __shfl_down(q, d); }
  __shared__ float ss[4], sq[4];
  const int wid = threadIdx.x >> 6;
  if ((threadIdx.x & 63) == 0) { ss[wid] = s; sq[wid] = q; }
  __syncthreads();
  const float fs = ss[0] + ss[1] + ss[2] + ss[3];
  const float fq = sq[0] + sq[1] + sq[2] + sq[3];
  const float mean = fs * (1.0f / 1024.0f);
  const float var = fq * (1.0f / 1024.0f) - mean * mean;
  const float rstd = rsqrtf(var + 1e-5f);
  const float4 w = *(const float4*)(W + c);
  float4 o;
  o.x = (v.x - mean) * rstd * w.x; o.y = (v.y - mean) * rstd * w.y;
  o.z = (v.z - mean) * rstd * w.z; o.w = (v.w - mean) * rstd * w.w;
  if (WF32) *(float4*)(Yf + (size_t)row * 1024 + c) = o;
  unsigned long long pk = (unsigned long long)f2b(o.x)
      | ((unsigned long long)f2b(o.y) << 16)
      | ((unsigned long long)f2b(o.z) << 32)
      | ((unsigned long long)f2b(o.w) << 48);
  *(unsigned long long*)(Yb + (size_t)row * 1024 + c) = pk;
}

// ---------------- weight transpose+convert ----------------
__global__ LB void transpose_w(const float* __restrict__ src, long long srcZ,
                               unsigned short* __restrict__ dst, long long dstZ,
                               int R, int C, int rowOff, int ldDst) {
  __shared__ float tile[32][33];
  const int z = blockIdx.z;
  const float* S = src + (size_t)z * srcZ;
  unsigned short* D = dst + (size_t)z * dstZ;
  const int c0 = blockIdx.x * 32, r0 = blockIdx.y * 32;
  const int tx = threadIdx.x & 31, ty = threadIdx.x >> 5;
  #pragma unroll
  for (int u = 0; u < 4; ++u)
    tile[ty + u * 8][tx] = S[(size_t)(r0 + ty + u * 8) * C + c0 + tx];
  __syncthreads();
  #pragma unroll
  for (int u = 0; u < 4; ++u)
    D[(size_t)(rowOff + c0 + ty + u * 8) * ldDst + r0 + tx] = f2b(tile[tx][ty + u * 8]);
}

// ---------------- v transpose ----------------
__global__ LB void transpose_v(const unsigned short* __restrict__ src, unsigned short* __restrict__ dst) {
  __shared__ unsigned short tile[32][33];
  const int b = blockIdx.z;
  const int c0 = blockIdx.x * 32, t0 = blockIdx.y * 32;
  const int tx = threadIdx.x & 31, ty = threadIdx.x >> 5;
  #pragma unroll
  for (int u = 0; u < 4; ++u)
    tile[ty + u * 8][tx] = src[(size_t)(b * 1024 + t0 + ty + u * 8) * 1536 + 1280 + c0 + tx];
  __syncthreads();
  #pragma unroll
  for (int u = 0; u < 4; ++u)
    dst[((size_t)b * 256 + c0 + ty + u * 8) * 1024 + t0 + tx] = tile[tx][ty + u * 8];
}

// ---------------- causal softmax ----------------
__global__ LB void softmax_causal(unsigned short* __restrict__ P) {
  const int i = blockIdx.x;
  const int head = blockIdx.y;
  unsigned short* row = P + ((size_t)head * 1024 + i) * 1024;
  const int tid = threadIdx.x;
  float sv[4];
  float mx = -1e30f;
  #pragma unroll
  for (int u = 0; u < 4; ++u) {
    const int j = tid + u * 256;
    const float s = (j <= i) ? b2f(row[j]) * 0.125f : -1e30f;
    sv[u] = s;
    mx = fmaxf(mx, s);
  }
  #pragma unroll
  for (int d = 32; d > 0; d >>= 1) mx = fmaxf(mx, __shfl_down(mx, d));
  __shared__ float sm[4];
  if ((tid & 63) == 0) sm[tid >> 6] = mx;
  __syncthreads();
  mx = fmaxf(fmaxf(sm[0], sm[1]), fmaxf(sm[2], sm[3]));
  float se = 0.0f;
  #pragma unroll
  for (int u = 0; u < 4; ++u) {
    const int j = tid + u * 256;
    const float e = (j <= i) ? __expf(sv[u] - mx) : 0.0f;
    sv[u] = e; se += e;
  }
  #pragma unroll
  for (int d = 32; d > 0; d >>= 1) se += __shfl_down(se, d);
  __shared__ float ssum[4];
  if ((tid & 63) == 0) ssum[tid >> 6] = se;
  __syncthreads();
  se = ssum[0] + ssum[1] + ssum[2] + ssum[3];
  const float inv = 1.0f / se;
  #pragma unroll
  for (int u = 0; u < 4; ++u) {
    const int j = tid + u * 256;
    row[j] = f2b(sv[u] * inv);
  }
}

// ---------------- NT GEMM: C[M,N] = A[M,K] * Bt[N,K]^T, bf16 in, f32 acc ----------------
// bx = M-tile, by = N-tile (M fastest-varying for B-panel L2 reuse).
// ATTN: 0 = linear batch strides (+XCD swizzle), 1 = QK^T head mode, 2 = PV head mode
template<int BM, int BN, bool BF16OUT, bool RELU, bool RESID, int ATTN, bool CAUSAL, bool KC>
__global__ LB void gemm_nt(const unsigned short* __restrict__ A, const unsigned short* __restrict__ Bt,
                           void* __restrict__ Cv, const float* __restrict__ Res,
                           int M, int N, int K, int lda, int ldb, int ldc,
                           long long sA, long long sB, long long sC) {
  (void)M; (void)N;
  constexpr int BK = 32;                      // K-step (ushorts); row = 64B
  constexpr int WM = BM / 2, WN = BN / 2;
  constexpr int FM = WM / 16, FN = WN / 16;
  constexpr int PA = (BM * 64) / 4096;        // staging passes (256 thr * 16B)
  constexpr int PB = (BN * 64) / 4096;
  const int bz = blockIdx.z;
  int bx, by;
  if (ATTN == 0) {
    int f = blockIdx.x + gridDim.x * blockIdx.y;
    const int n = gridDim.x * gridDim.y;
    if ((n & 7) == 0) f = (f & 7) * (n >> 3) + (f >> 3);   // T1 XCD chunk swizzle
    bx = f % gridDim.x; by = f / gridDim.x;
  } else {
    bx = blockIdx.x; by = blockIdx.y;
  }
  if (CAUSAL && by > bx) return;              // requires BM==BN

  long long aoff, boff, coff;
  if (ATTN == 1) {
    const int b = bz >> 4, hh = bz & 15, n = hh & 3;
    aoff = (long long)b * sA + hh * 64;
    boff = (long long)b * sB + 1024 + n * 64;
    coff = (long long)bz * sC;
  } else if (ATTN == 2) {
    const int b = bz >> 4, hh = bz & 15, n = hh & 3;
    aoff = (long long)bz * sA;
    boff = (long long)(b * 4 + n) * sB;
    coff = (long long)b * sC + hh * 64;
  } else {
    aoff = (long long)bz * sA; boff = (long long)bz * sB; coff = (long long)bz * sC;
  }
  const unsigned short* Ab = A + aoff;
  const unsigned short* Bb = Bt + boff;

  const int tid = threadIdx.x;
  const int lane = tid & 63, wid = tid >> 6;
  const int wr = wid >> 1, wc = wid & 1;
  const int m0 = bx * BM, n0 = by * BN;

  __shared__ unsigned short lsA[BM * BK];
  __shared__ unsigned short lsB[BN * BK];

  f32x4 acc[FM][FN] = {};

  // staging addresses: thread t covers 16B at row t/4, ushort-col (t%4)*8
  const int r4 = tid >> 2;
  const int kp = (tid & 3) << 3;
  const unsigned short* gA = Ab + (size_t)(m0 + r4) * lda + kp;
  const unsigned short* gB = Bb + (size_t)(n0 + r4) * ldb + kp;
  unsigned short* lA = lsA + tid * 8;
  unsigned short* lB = lsB + tid * 8;

  const int Kend = KC ? (m0 + BM < K ? m0 + BM : K) : K;

  for (int k0 = 0; k0 < Kend; k0 += BK) {
    if (k0) __syncthreads();                  // readers done with LDS
    #pragma unroll
    for (int p = 0; p < PA; ++p)
      GLDS(gA + (size_t)p * 64 * lda + k0, lA + p * 2048);
    #pragma unroll
    for (int p = 0; p < PB; ++p)
      GLDS(gB + (size_t)p * 64 * ldb + k0, lB + p * 2048);
    __syncthreads();                          // drains vmcnt before barrier

    const int kk = (lane >> 4) * 8;
    bf16x8 af[FM], bfv[FN];
    #pragma unroll
    for (int mi = 0; mi < FM; ++mi)
      af[mi] = *(const bf16x8*)&lsA[(wr * WM + mi * 16 + (lane & 15)) * BK + kk];
    #pragma unroll
    for (int nj = 0; nj < FN; ++nj)
      bfv[nj] = *(const bf16x8*)&lsB[(wc * WN + nj * 16 + (lane & 15)) * BK + kk];
    #pragma unroll
    for (int mi = 0; mi < FM; ++mi)
      #pragma unroll
      for (int nj = 0; nj < FN; ++nj)
        acc[mi][nj] = __builtin_amdgcn_mfma_f32_16x16x32_bf16(af[mi], bfv[nj], acc[mi][nj], 0, 0, 0);
  }

  // epilogue: C/D layout col=lane&15, row=(lane>>4)*4+reg  [m89-verified]
  const int r0 = (lane >> 4) * 4, c0 = lane & 15;
  #pragma unroll
  for (int mi = 0; mi < FM; ++mi) {
    #pragma unroll
    for (int nj = 0; nj < FN; ++nj) {
      const int c = n0 + wc * WN + nj * 16 + c0;
      #pragma unroll
      for (int j = 0; j < 4; ++j) {
        const int r = m0 + wr * WM + mi * 16 + r0 + j;
        float v = acc[mi][nj][j];
        if (RELU) v = fmaxf(v, 0.0f);
        if (RESID) v += Res[(size_t)r * ldc + c];
        const size_t o = (size_t)coff + (size_t)r * ldc + c;
        if (BF16OUT) ((unsigned short*)Cv)[o] = f2b(v);
        else ((float*)Cv)[o] = v;
      }
    }
  }
}

extern "C" void kernel_launch(void* const* d_in, const int* in_sizes, int n_in,
                              void* d_out, int out_size, void* d_ws, size_t ws_size,
                              hipStream_t stream) {
  (void)in_sizes; (void)n_in; (void)out_size;
  const int*   idx      = (const int*)d_in[0];
  const float* tok_emb  = (const float*)d_in[1];
  const float* pos_emb  = (const float*)d_in[2];
  const float* q_proj   = (const float*)d_in[3];
  const float* kv_proj  = (const float*)d_in[4];
  const float* out_proj = (const float*)d_in[5];
  const float* fc_in    = (const float*)d_in[6];
  const float* fc_out   = (const float*)d_in[7];
  const float* scale    = (const float*)d_in[8];
  const float* out_scl  = (const float*)d_in[9];
  const float* lm_head  = (const float*)d_in[10];
  float* out = (float*)d_out;

  char* ws = (char*)d_ws;
  size_t off = 0;
  auto alloc = [&](size_t bytes) -> void* {
    void* p = ws + off;
    off += (bytes + 255) & ~(size_t)255;
    return p;
  };
  unsigned short* WqkvT = (unsigned short*)alloc((size_t)1536 * 1024 * 2);
  unsigned short* WoT   = (unsigned short*)alloc((size_t)1024 * 1024 * 2);
  unsigned short* F1T   = (unsigned short*)alloc((size_t)4096 * 1024 * 2);
  unsigned short* F2T   = (unsigned short*)alloc((size_t)1024 * 4096 * 2);
  float*  xbuf  = (float*)alloc((size_t)2048 * 1024 * 4);
  float*  hbuf  = (float*)alloc((size_t)2048 * 1024 * 4);
  float*  h2buf = (float*)alloc((size_t)2048 * 1024 * 4);
  unsigned short* actb  = (unsigned short*)alloc((size_t)2048 * 1024 * 2);
  unsigned short* qkvb  = (unsigned short*)alloc((size_t)2048 * 1536 * 2);
  unsigned short* vT    = (unsigned short*)alloc((size_t)2 * 256 * 1024 * 2);
  unsigned short* probs = (unsigned short*)alloc((size_t)32 * 1024 * 1024 * 2);
  unsigned short* ob    = (unsigned short*)alloc((size_t)2048 * 1024 * 2);
  unsigned short* m1    = (unsigned short*)alloc((size_t)2048 * 4096 * 2);
  if (off > ws_size) return;

  const dim3 thr(256);

  embed_kernel<<<dim3(2048), thr, 0, stream>>>(idx, tok_emb, pos_emb, xbuf);

  for (int l = 0; l < 8; ++l) {
    transpose_w<<<dim3(32, 32, 1), thr, 0, stream>>>(q_proj + (size_t)l * 1024 * 1024, 0, WqkvT, 0, 1024, 1024, 0, 1024);
    transpose_w<<<dim3(8, 32, 1), thr, 0, stream>>>(kv_proj + (size_t)l * 2 * 1024 * 256, 0, WqkvT, 0, 1024, 256, 1024, 1024);
    transpose_w<<<dim3(8, 32, 1), thr, 0, stream>>>(kv_proj + (size_t)l * 2 * 1024 * 256 + 1024 * 256, 0, WqkvT, 0, 1024, 256, 1280, 1024);
    transpose_w<<<dim3(32, 32, 1), thr, 0, stream>>>(out_proj + (size_t)l * 1024 * 1024, 0, WoT, 0, 1024, 1024, 0, 1024);
    transpose_w<<<dim3(128, 32, 1), thr, 0, stream>>>(fc_in + (size_t)l * 1024 * 4096, 0, F1T, 0, 1024, 4096, 0, 1024);
    transpose_w<<<dim3(32, 128, 1), thr, 0, stream>>>(fc_out + (size_t)l * 4096 * 1024, 0, F2T, 0, 4096, 1024, 0, 4096);

    const float* w1 = scale + (size_t)l * 2048;
    const float* w2 = w1 + 1024;

    ln_kernel<true><<<dim3(2048), thr, 0, stream>>>(xbuf, w1, hbuf, actb);
    // qkv = h @ Wqkv
    gemm_nt<128, 128, true, false, false, 0, false, false><<<dim3(16, 12, 1), thr, 0, stream>>>(
        actb, WqkvT, qkvb, nullptr, 2048, 1536, 1024, 1024, 1024, 1536, 0, 0, 0);
    transpose_v<<<dim3(8, 32, 2), thr, 0, stream>>>(qkvb, vT);
    // scores = Q K^T (causal tile skip)
    gemm_nt<128, 128, true, false, false, 1, true, false><<<dim3(8, 8, 32), thr, 0, stream>>>(
        qkvb, qkvb, probs, nullptr, 1024, 1024, 64, 1536, 1536, 1024,
        1536LL * 1024, 1536LL * 1024, 1024LL * 1024);
    softmax_causal<<<dim3(1024, 32), thr, 0, stream>>>(probs);
    // o = P @ V (K truncated at causal boundary)
    gemm_nt<128, 64, true, false, false, 2, false, true><<<dim3(8, 1, 32), thr, 0, stream>>>(
        probs, vT, ob, nullptr, 1024, 64, 1024, 1024, 1024, 1024,
        1024LL * 1024, 64LL * 1024, 1024LL * 1024);
    // x = h + o @ Wo
    gemm_nt<128, 128, false, false, true, 0, false, false><<<dim3(16, 8, 1), thr, 0, stream>>>(
        ob, WoT, xbuf, hbuf, 2048, 1024, 1024, 1024, 1024, 1024, 0, 0, 0);
    ln_kernel<true><<<dim3(2048), thr, 0, stream>>>(xbuf, w2, h2buf, actb);
    // m1 = relu(h2 @ fc1)
    gemm_nt<128, 128, true, true, false, 0, false, false><<<dim3(16, 32, 1), thr, 0, stream>>>(
        actb, F1T, m1, nullptr, 2048, 4096, 1024, 1024, 1024, 4096, 0, 0, 0);
    // x = h2 + m1 @ fc2
    gemm_nt<128, 128, false, false, true, 0, false, false><<<dim3(16, 8, 1), thr, 0, stream>>>(
        m1, F2T, xbuf, h2buf, 2048, 1024, 4096, 4096, 4096, 1024, 0, 0, 0);
  }

  unsigned short* LmT = probs;
  transpose_w<<<dim3(1000, 32, 1), thr, 0, stream>>>(lm_head, 0, LmT, 0, 1024, 32000, 0, 1024);
  ln_kernel<false><<<dim3(2048), thr, 0, stream>>>(xbuf, out_scl, nullptr, actb);
  gemm_nt<128, 128, false, false, false, 0, false, false><<<dim3(16, 250, 1), thr, 0, stream>>>(
      actb, LmT, out, nullptr, 2048, 32000, 1024, 1024, 1024, 32000, 0, 0, 0);
}

// Round 3
// 1998.297 us; speedup vs baseline: 1.3396x; 1.2214x over previous
//
#include <hip/hip_runtime.h>
#include <hip/hip_bf16.h>

typedef __attribute__((ext_vector_type(8))) short bf16x8;
typedef __attribute__((ext_vector_type(4))) float f32x4;

#define LB __launch_bounds__(256)

__device__ __forceinline__ unsigned short f2b(float f) {
  __hip_bfloat16 h = __float2bfloat16(f);
  return __builtin_bit_cast(unsigned short, h);
}
__device__ __forceinline__ float b2f(unsigned short u) {
  __hip_bfloat16 h = __builtin_bit_cast(__hip_bfloat16, u);
  return __bfloat162float(h);
}

// async global->LDS, 16B per lane. LDS dest must be wave-uniform base + lane*16.
#define GLDS(gp, lp)                                                        \
  __builtin_amdgcn_global_load_lds(                                         \
      (const __attribute__((address_space(1))) void*)(gp),                  \
      (__attribute__((address_space(3))) void*)(lp), 16, 0, 0)

// ---------------- embed ----------------
__global__ LB void embed_kernel(const int* __restrict__ idx, const float* __restrict__ tok,
                                const float* __restrict__ pos, float* __restrict__ X) {
  const int m = blockIdx.x;
  const int t = m & 1023;
  const int token = idx[m];
  const int c = threadIdx.x * 4;
  const float4 a = *(const float4*)(tok + (size_t)token * 1024 + c);
  const float4 p = *(const float4*)(pos + (size_t)t * 1024 + c);
  float4 o; o.x = a.x + p.x; o.y = a.y + p.y; o.z = a.z + p.z; o.w = a.w + p.w;
  *(float4*)(X + (size_t)m * 1024 + c) = o;
}

// ---------------- layernorm ----------------
template<bool WF32>
__global__ LB void ln_kernel(const float* __restrict__ X, const float* __restrict__ W,
                             float* __restrict__ Yf, unsigned short* __restrict__ Yb) {
  const int row = blockIdx.x;
  const float* xr = X + (size_t)row * 1024;
  const int c = threadIdx.x * 4;
  const float4 v = *(const float4*)(xr + c);
  float s = v.x + v.y + v.z + v.w;
  float q = v.x*v.x + v.y*v.y + v.z*v.z + v.w*v.w;
  #pragma unroll
  for (int d = 32; d > 0; d >>= 1) { s += __shfl_down(s, d); q += __shfl_down(q, d); }
  __shared__ float ss[4], sq[4];
  const int wid = threadIdx.x >> 6;
  if ((threadIdx.x & 63) == 0) { ss[wid] = s; sq[wid] = q; }
  __syncthreads();
  const float fs = ss[0] + ss[1] + ss[2] + ss[3];
  const float fq = sq[0] + sq[1] + sq[2] + sq[3];
  const float mean = fs * (1.0f / 1024.0f);
  const float var = fq * (1.0f / 1024.0f) - mean * mean;
  const float rstd = rsqrtf(var + 1e-5f);
  const float4 w = *(const float4*)(W + c);
  float4 o;
  o.x = (v.x - mean) * rstd * w.x; o.y = (v.y - mean) * rstd * w.y;
  o.z = (v.z - mean) * rstd * w.z; o.w = (v.w - mean) * rstd * w.w;
  if (WF32) *(float4*)(Yf + (size_t)row * 1024 + c) = o;
  unsigned long long pk = (unsigned long long)f2b(o.x)
      | ((unsigned long long)f2b(o.y) << 16)
      | ((unsigned long long)f2b(o.z) << 32)
      | ((unsigned long long)f2b(o.w) << 48);
  *(unsigned long long*)(Yb + (size_t)row * 1024 + c) = pk;
}

// ---------------- weight transpose+convert: dst[rowOff+c][r] = bf16(src[r][c]) ----------------
__global__ LB void transpose_w(const float* __restrict__ src, unsigned short* __restrict__ dst,
                               int C, int rowOff, int ldDst) {
  __shared__ float tile[32][33];
  const int c0 = blockIdx.x * 32, r0 = blockIdx.y * 32;
  const int tx = threadIdx.x & 31, ty = threadIdx.x >> 5;
  #pragma unroll
  for (int u = 0; u < 4; ++u)
    tile[ty + u * 8][tx] = src[(size_t)(r0 + ty + u * 8) * C + c0 + tx];
  __syncthreads();
  const int ci = threadIdx.x >> 4;      // 0..15
  const int rp = threadIdx.x & 15;      // 0..15 -> rows rp*2, rp*2+1
  #pragma unroll
  for (int u = 0; u < 2; ++u) {
    const int c = ci + u * 16;
    unsigned int pk = (unsigned int)f2b(tile[rp * 2][c])
                    | ((unsigned int)f2b(tile[rp * 2 + 1][c]) << 16);
    *(unsigned int*)&dst[(size_t)(rowOff + c0 + c) * ldDst + r0 + rp * 2] = pk;
  }
}

// ---------------- v transpose: vT[b][n*64+d][t] ----------------
__global__ LB void transpose_v(const unsigned short* __restrict__ src, unsigned short* __restrict__ dst) {
  __shared__ unsigned short tile[32][33];
  const int b = blockIdx.z;
  const int c0 = blockIdx.x * 32, t0 = blockIdx.y * 32;
  const int tx = threadIdx.x & 31, ty = threadIdx.x >> 5;
  #pragma unroll
  for (int u = 0; u < 4; ++u)
    tile[ty + u * 8][tx] = src[(size_t)(b * 1024 + t0 + ty + u * 8) * 1536 + 1280 + c0 + tx];
  __syncthreads();
  #pragma unroll
  for (int u = 0; u < 4; ++u)
    dst[((size_t)b * 256 + c0 + ty + u * 8) * 1024 + t0 + tx] = tile[tx][ty + u * 8];
}

// ---------------- causal softmax (bounded loads/stores) ----------------
__global__ LB void softmax_causal(unsigned short* __restrict__ P) {
  const int i = blockIdx.x;
  const int head = blockIdx.y;
  unsigned short* row = P + ((size_t)head * 1024 + i) * 1024;
  const int tid = threadIdx.x;
  const int jend = (i & ~127) + 128;      // PV reads zeros up to tile boundary
  float sv[4];
  float mx = -1e30f;
  #pragma unroll
  for (int u = 0; u < 4; ++u) {
    const int j = tid + u * 256;
    float s = -1e30f;
    if (j <= i) s = b2f(row[j]) * 0.125f;
    sv[u] = s;
    mx = fmaxf(mx, s);
  }
  #pragma unroll
  for (int d = 32; d > 0; d >>= 1) mx = fmaxf(mx, __shfl_down(mx, d));
  __shared__ float sm[4];
  if ((tid & 63) == 0) sm[tid >> 6] = mx;
  __syncthreads();
  mx = fmaxf(fmaxf(sm[0], sm[1]), fmaxf(sm[2], sm[3]));
  float se = 0.0f;
  #pragma unroll
  for (int u = 0; u < 4; ++u) {
    const int j = tid + u * 256;
    const float e = (j <= i) ? __expf(sv[u] - mx) : 0.0f;
    sv[u] = e; se += e;
  }
  #pragma unroll
  for (int d = 32; d > 0; d >>= 1) se += __shfl_down(se, d);
  __shared__ float ssum[4];
  if ((tid & 63) == 0) ssum[tid >> 6] = se;
  __syncthreads();
  se = ssum[0] + ssum[1] + ssum[2] + ssum[3];
  const float inv = 1.0f / se;
  #pragma unroll
  for (int u = 0; u < 4; ++u) {
    const int j = tid + u * 256;
    if (j < jend) row[j] = f2b(sv[u] * inv);
  }
}

// ---------------- NT GEMM: C[M,N] = A[M,K] * Bt[N,K]^T, bf16 in, f32 acc ----------------
// BK=64 (128B LDS rows), XOR chunk swizzle: LDS[row][ch] holds global chunk ch^(row&7).
// Store side: pre-swizzled GLOBAL source column (per-thread constant), linear LDS dest.
// Read side: chunk = (ks*4 + lane>>4) ^ (lane&7)  -> conflict-free b128 reads.
// bx = M-tile, by = N-tile (M fastest for B-panel L2 reuse). ATTN: 0 linear (+XCD swizzle),
// 1 = QK^T head mode, 2 = PV head mode.
template<int BM, int BN, bool BF16OUT, bool RELU, bool RESID, int ATTN, bool CAUSAL, bool KC>
__global__ LB void gemm_nt(const unsigned short* __restrict__ A, const unsigned short* __restrict__ Bt,
                           void* __restrict__ Cv, const float* __restrict__ Res,
                           int M, int N, int K, int lda, int ldb, int ldc,
                           long long sA, long long sB, long long sC) {
  (void)M; (void)N;
  constexpr int BK = 64;
  constexpr int WM = BM / 2, WN = BN / 2;
  constexpr int FM = WM / 16, FN = WN / 16;
  constexpr int PA = BM / 32, PB = BN / 32;   // staging passes (256 thr * 16B = 32 rows)
  const int bz = blockIdx.z;
  int bx, by;
  if (ATTN == 0) {
    int f = blockIdx.x + gridDim.x * blockIdx.y;
    const int n = gridDim.x * gridDim.y;
    if ((n & 7) == 0) f = (f & 7) * (n >> 3) + (f >> 3);   // T1 XCD chunk swizzle
    bx = f % gridDim.x; by = f / gridDim.x;
  } else {
    bx = blockIdx.x; by = blockIdx.y;
  }
  if (CAUSAL && by > bx) return;              // requires BM==BN

  long long aoff, boff, coff;
  if (ATTN == 1) {
    const int b = bz >> 4, hh = bz & 15, n = hh & 3;
    aoff = (long long)b * sA + hh * 64;
    boff = (long long)b * sB + 1024 + n * 64;
    coff = (long long)bz * sC;
  } else if (ATTN == 2) {
    const int b = bz >> 4, hh = bz & 15, n = hh & 3;
    aoff = (long long)bz * sA;
    boff = (long long)(b * 4 + n) * sB;
    coff = (long long)b * sC + hh * 64;
  } else {
    aoff = (long long)bz * sA; boff = (long long)bz * sB; coff = (long long)bz * sC;
  }
  const unsigned short* Ab = A + aoff;
  const unsigned short* Bb = Bt + boff;

  const int tid = threadIdx.x;
  const int lane = tid & 63, wid = tid >> 6;
  const int wr = wid >> 1, wc = wid & 1;
  const int m0 = bx * BM, n0 = by * BN;

  __shared__ unsigned short lsA[BM * BK];
  __shared__ unsigned short lsB[BN * BK];

  f32x4 acc[FM][FN] = {};

  // staging: thread t -> LDS (row = t/8 + 32p, chunk = t&7); global col = (chunk ^ row&7)*8
  const int srow = tid >> 3;
  const int scol = ((tid & 7) ^ (srow & 7)) << 3;
  const unsigned short* gA = Ab + (size_t)(m0 + srow) * lda + scol;
  const unsigned short* gB = Bb + (size_t)(n0 + srow) * ldb + scol;
  unsigned short* lA = lsA + tid * 8;
  unsigned short* lB = lsB + tid * 8;

  const int fr = lane & 15;
  const int j7 = lane & 7;
  const int g4 = lane >> 4;

  const int Kend = KC ? (m0 + BM < K ? m0 + BM : K) : K;

  for (int k0 = 0; k0 < Kend; k0 += BK) {
    if (k0) __syncthreads();
    #pragma unroll
    for (int p = 0; p < PA; ++p)
      GLDS(gA + (size_t)(p * 32) * lda + k0, lA + p * 2048);
    #pragma unroll
    for (int p = 0; p < PB; ++p)
      GLDS(gB + (size_t)(p * 32) * ldb + k0, lB + p * 2048);
    __syncthreads();

    #pragma unroll
    for (int ks = 0; ks < 2; ++ks) {
      const int col = (((ks * 4 + g4) ^ j7) << 3);
      bf16x8 af[FM], bfv[FN];
      #pragma unroll
      for (int mi = 0; mi < FM; ++mi)
        af[mi] = *(const bf16x8*)&lsA[(wr * WM + mi * 16 + fr) * BK + col];
      #pragma unroll
      for (int nj = 0; nj < FN; ++nj)
        bfv[nj] = *(const bf16x8*)&lsB[(wc * WN + nj * 16 + fr) * BK + col];
      #pragma unroll
      for (int mi = 0; mi < FM; ++mi)
        #pragma unroll
        for (int nj = 0; nj < FN; ++nj)
          acc[mi][nj] = __builtin_amdgcn_mfma_f32_16x16x32_bf16(af[mi], bfv[nj], acc[mi][nj], 0, 0, 0);
    }
  }

  // epilogue: C/D layout col=lane&15, row=(lane>>4)*4+reg  [m89-verified]
  const int r0 = (lane >> 4) * 4, c0 = lane & 15;
  #pragma unroll
  for (int mi = 0; mi < FM; ++mi) {
    #pragma unroll
    for (int nj = 0; nj < FN; ++nj) {
      const int c = n0 + wc * WN + nj * 16 + c0;
      #pragma unroll
      for (int j = 0; j < 4; ++j) {
        const int r = m0 + wr * WM + mi * 16 + r0 + j;
        float v = acc[mi][nj][j];
        if (RELU) v = fmaxf(v, 0.0f);
        if (RESID) v += Res[(size_t)r * ldc + c];
        const size_t o = (size_t)coff + (size_t)r * ldc + c;
        if (BF16OUT) ((unsigned short*)Cv)[o] = f2b(v);
        else ((float*)Cv)[o] = v;
      }
    }
  }
}

extern "C" void kernel_launch(void* const* d_in, const int* in_sizes, int n_in,
                              void* d_out, int out_size, void* d_ws, size_t ws_size,
                              hipStream_t stream) {
  (void)in_sizes; (void)n_in; (void)out_size;
  const int*   idx      = (const int*)d_in[0];
  const float* tok_emb  = (const float*)d_in[1];
  const float* pos_emb  = (const float*)d_in[2];
  const float* q_proj   = (const float*)d_in[3];
  const float* kv_proj  = (const float*)d_in[4];
  const float* out_proj = (const float*)d_in[5];
  const float* fc_in    = (const float*)d_in[6];
  const float* fc_out   = (const float*)d_in[7];
  const float* scale    = (const float*)d_in[8];
  const float* out_scl  = (const float*)d_in[9];
  const float* lm_head  = (const float*)d_in[10];
  float* out = (float*)d_out;

  char* ws = (char*)d_ws;
  size_t off = 0;
  auto alloc = [&](size_t bytes) -> void* {
    void* p = ws + off;
    off += (bytes + 255) & ~(size_t)255;
    return p;
  };
  unsigned short* WqkvT = (unsigned short*)alloc((size_t)1536 * 1024 * 2);
  unsigned short* WoT   = (unsigned short*)alloc((size_t)1024 * 1024 * 2);
  unsigned short* F1T   = (unsigned short*)alloc((size_t)4096 * 1024 * 2);
  unsigned short* F2T   = (unsigned short*)alloc((size_t)1024 * 4096 * 2);
  float*  xbuf  = (float*)alloc((size_t)2048 * 1024 * 4);
  float*  hbuf  = (float*)alloc((size_t)2048 * 1024 * 4);
  float*  h2buf = (float*)alloc((size_t)2048 * 1024 * 4);
  unsigned short* actb  = (unsigned short*)alloc((size_t)2048 * 1024 * 2);
  unsigned short* qkvb  = (unsigned short*)alloc((size_t)2048 * 1536 * 2);
  unsigned short* vT    = (unsigned short*)alloc((size_t)2 * 256 * 1024 * 2);
  unsigned short* probs = (unsigned short*)alloc((size_t)32 * 1024 * 1024 * 2);
  unsigned short* ob    = (unsigned short*)alloc((size_t)2048 * 1024 * 2);
  unsigned short* m1    = (unsigned short*)alloc((size_t)2048 * 4096 * 2);
  if (off > ws_size) return;

  const dim3 thr(256);

  embed_kernel<<<dim3(2048), thr, 0, stream>>>(idx, tok_emb, pos_emb, xbuf);

  for (int l = 0; l < 8; ++l) {
    transpose_w<<<dim3(32, 32), thr, 0, stream>>>(q_proj + (size_t)l * 1024 * 1024, WqkvT, 1024, 0, 1024);
    transpose_w<<<dim3(8, 32), thr, 0, stream>>>(kv_proj + (size_t)l * 2 * 1024 * 256, WqkvT, 256, 1024, 1024);
    transpose_w<<<dim3(8, 32), thr, 0, stream>>>(kv_proj + (size_t)l * 2 * 1024 * 256 + 1024 * 256, WqkvT, 256, 1280, 1024);
    transpose_w<<<dim3(32, 32), thr, 0, stream>>>(out_proj + (size_t)l * 1024 * 1024, WoT, 1024, 0, 1024);
    transpose_w<<<dim3(128, 32), thr, 0, stream>>>(fc_in + (size_t)l * 1024 * 4096, F1T, 4096, 0, 1024);
    transpose_w<<<dim3(32, 128), thr, 0, stream>>>(fc_out + (size_t)l * 4096 * 1024, F2T, 1024, 0, 4096);

    const float* w1 = scale + (size_t)l * 2048;
    const float* w2 = w1 + 1024;

    ln_kernel<true><<<dim3(2048), thr, 0, stream>>>(xbuf, w1, hbuf, actb);
    // qkv = h @ Wqkv   (BN=64 -> 384 blocks)
    gemm_nt<128, 64, true, false, false, 0, false, false><<<dim3(16, 24), thr, 0, stream>>>(
        actb, WqkvT, qkvb, nullptr, 2048, 1536, 1024, 1024, 1024, 1536, 0, 0, 0);
    transpose_v<<<dim3(8, 32, 2), thr, 0, stream>>>(qkvb, vT);
    // scores = Q K^T (causal tile skip)
    gemm_nt<128, 128, true, false, false, 1, true, false><<<dim3(8, 8, 32), thr, 0, stream>>>(
        qkvb, qkvb, probs, nullptr, 1024, 1024, 64, 1536, 1536, 1024,
        1536LL * 1024, 1536LL * 1024, 1024LL * 1024);
    softmax_causal<<<dim3(1024, 32), thr, 0, stream>>>(probs);
    // o = P @ V (K truncated at causal boundary)
    gemm_nt<128, 64, true, false, false, 2, false, true><<<dim3(8, 1, 32), thr, 0, stream>>>(
        probs, vT, ob, nullptr, 1024, 64, 1024, 1024, 1024, 1024,
        1024LL * 1024, 64LL * 1024, 1024LL * 1024);
    // x = h + o @ Wo   (BN=64 -> 256 blocks)
    gemm_nt<128, 64, false, false, true, 0, false, false><<<dim3(16, 16), thr, 0, stream>>>(
        ob, WoT, xbuf, hbuf, 2048, 1024, 1024, 1024, 1024, 1024, 0, 0, 0);
    ln_kernel<true><<<dim3(2048), thr, 0, stream>>>(xbuf, w2, h2buf, actb);
    // m1 = relu(h2 @ fc1)
    gemm_nt<128, 128, true, true, false, 0, false, false><<<dim3(16, 32), thr, 0, stream>>>(
        actb, F1T, m1, nullptr, 2048, 4096, 1024, 1024, 1024, 4096, 0, 0, 0);
    // x = h2 + m1 @ fc2   (BN=64 -> 256 blocks)
    gemm_nt<128, 64, false, false, true, 0, false, false><<<dim3(16, 16), thr, 0, stream>>>(
        m1, F2T, xbuf, h2buf, 2048, 1024, 4096, 4096, 4096, 1024, 0, 0, 0);
  }

  unsigned short* LmT = probs;
  transpose_w<<<dim3(1000, 32), thr, 0, stream>>>(lm_head, LmT, 32000, 0, 1024);
  ln_kernel<false><<<dim3(2048), thr, 0, stream>>>(xbuf, out_scl, nullptr, actb);
  gemm_nt<128, 128, false, false, false, 0, false, false><<<dim3(16, 250), thr, 0, stream>>>(
      actb, LmT, out, nullptr, 2048, 32000, 1024, 1024, 1024, 32000, 0, 0, 0);
}

// Round 4
// 1757.862 us; speedup vs baseline: 1.5229x; 1.1368x over previous
//
#include <hip/hip_runtime.h>
#include <hip/hip_bf16.h>

typedef __attribute__((ext_vector_type(8))) short bf16x8;
typedef __attribute__((ext_vector_type(4))) short bf16x4;
typedef __attribute__((ext_vector_type(4))) float f32x4;

#define LB __launch_bounds__(256)

__device__ __forceinline__ unsigned short f2b(float f) {
  __hip_bfloat16 h = __float2bfloat16(f);
  return __builtin_bit_cast(unsigned short, h);
}

// async global->LDS, 16B per lane. LDS dest must be wave-uniform base + lane*16.
#define GLDS(gp, lp)                                                        \
  __builtin_amdgcn_global_load_lds(                                         \
      (const __attribute__((address_space(1))) void*)(gp),                  \
      (__attribute__((address_space(3))) void*)(lp), 16, 0, 0)

// ---------------- embed ----------------
__global__ LB void embed_kernel(const int* __restrict__ idx, const float* __restrict__ tok,
                                const float* __restrict__ pos, float* __restrict__ X) {
  const int m = blockIdx.x;
  const int t = m & 1023;
  const int token = idx[m];
  const int c = threadIdx.x * 4;
  const float4 a = *(const float4*)(tok + (size_t)token * 1024 + c);
  const float4 p = *(const float4*)(pos + (size_t)t * 1024 + c);
  float4 o; o.x = a.x + p.x; o.y = a.y + p.y; o.z = a.z + p.z; o.w = a.w + p.w;
  *(float4*)(X + (size_t)m * 1024 + c) = o;
}

// ---------------- layernorm ----------------
template<bool WF32>
__global__ LB void ln_kernel(const float* __restrict__ X, const float* __restrict__ W,
                             float* __restrict__ Yf, unsigned short* __restrict__ Yb) {
  const int row = blockIdx.x;
  const float* xr = X + (size_t)row * 1024;
  const int c = threadIdx.x * 4;
  const float4 v = *(const float4*)(xr + c);
  float s = v.x + v.y + v.z + v.w;
  float q = v.x*v.x + v.y*v.y + v.z*v.z + v.w*v.w;
  #pragma unroll
  for (int d = 32; d > 0; d >>= 1) { s += __shfl_down(s, d); q += __shfl_down(q, d); }
  __shared__ float ss[4], sq[4];
  const int wid = threadIdx.x >> 6;
  if ((threadIdx.x & 63) == 0) { ss[wid] = s; sq[wid] = q; }
  __syncthreads();
  const float fs = ss[0] + ss[1] + ss[2] + ss[3];
  const float fq = sq[0] + sq[1] + sq[2] + sq[3];
  const float mean = fs * (1.0f / 1024.0f);
  const float var = fq * (1.0f / 1024.0f) - mean * mean;
  const float rstd = rsqrtf(var + 1e-5f);
  const float4 w = *(const float4*)(W + c);
  float4 o;
  o.x = (v.x - mean) * rstd * w.x; o.y = (v.y - mean) * rstd * w.y;
  o.z = (v.z - mean) * rstd * w.z; o.w = (v.w - mean) * rstd * w.w;
  if (WF32) *(float4*)(Yf + (size_t)row * 1024 + c) = o;
  unsigned long long pk = (unsigned long long)f2b(o.x)
      | ((unsigned long long)f2b(o.y) << 16)
      | ((unsigned long long)f2b(o.z) << 32)
      | ((unsigned long long)f2b(o.w) << 48);
  *(unsigned long long*)(Yb + (size_t)row * 1024 + c) = pk;
}

// ---------------- weight transpose+convert: dst[rowOff+c][r] = bf16(src[r][c]) ----------------
__global__ LB void transpose_w(const float* __restrict__ src, unsigned short* __restrict__ dst,
                               int C, int rowOff, int ldDst) {
  __shared__ float tile[32][33];
  const int c0 = blockIdx.x * 32, r0 = blockIdx.y * 32;
  const int tx = threadIdx.x & 31, ty = threadIdx.x >> 5;
  #pragma unroll
  for (int u = 0; u < 4; ++u)
    tile[ty + u * 8][tx] = src[(size_t)(r0 + ty + u * 8) * C + c0 + tx];
  __syncthreads();
  const int ci = threadIdx.x >> 4;
  const int rp = threadIdx.x & 15;
  #pragma unroll
  for (int u = 0; u < 2; ++u) {
    const int c = ci + u * 16;
    unsigned int pk = (unsigned int)f2b(tile[rp * 2][c])
                    | ((unsigned int)f2b(tile[rp * 2 + 1][c]) << 16);
    *(unsigned int*)&dst[(size_t)(rowOff + c0 + c) * ldDst + r0 + rp * 2] = pk;
  }
}

// ---------------- v transpose: vT[b][n*64+d][t] ----------------
__global__ LB void transpose_v(const unsigned short* __restrict__ src, unsigned short* __restrict__ dst) {
  __shared__ unsigned short tile[32][33];
  const int b = blockIdx.z;
  const int c0 = blockIdx.x * 32, t0 = blockIdx.y * 32;
  const int tx = threadIdx.x & 31, ty = threadIdx.x >> 5;
  #pragma unroll
  for (int u = 0; u < 4; ++u)
    tile[ty + u * 8][tx] = src[(size_t)(b * 1024 + t0 + ty + u * 8) * 1536 + 1280 + c0 + tx];
  __syncthreads();
  #pragma unroll
  for (int u = 0; u < 4; ++u)
    dst[((size_t)b * 256 + c0 + ty + u * 8) * 1024 + t0 + tx] = tile[tx][ty + u * 8];
}

// ---------------- fused flash attention ----------------
// Grid (8 q-tiles, 32 b*head). Block 256 thr = 4 waves; wave w owns q rows
// [qt*128 + w*32, +32). K/V [64x64] tiles staged via GLDS with XOR chunk swizzle.
// Swapped QK^T: S^T = mfma(K, Q) so lane holds S[k][q=c]; row stats via
// shfl_xor(16/32); P packed b64 into per-wave swizzled LDS; PV reads it as A-frag.
__global__ LB void attn_fused(const unsigned short* __restrict__ qkvb,
                              const unsigned short* __restrict__ vT,
                              unsigned short* __restrict__ ob) {
  const int qt = blockIdx.x, bh = blockIdx.y;
  const int b = bh >> 4, hh = bh & 15, n = hh & 3;
  const int tid = threadIdx.x, lane = tid & 63, w = tid >> 6;
  const int g = lane >> 4, c = lane & 15;
  const int q0w = qt * 128 + w * 32;
  const int kdiag = q0w >> 6;            // wave's diagonal k-tile

  __shared__ unsigned short lsK[64 * 64];
  __shared__ unsigned short lsV[64 * 64];
  __shared__ unsigned short lsP[4][32 * 64];
  unsigned short* Pw = lsP[w];

  // Q fragments (B operand): lane: q-col = nj*16+c, d-chunk = ks*32+g*8
  bf16x8 qf[2][2];
  {
    const unsigned short* Qb = qkvb + (size_t)(b * 1024 + q0w) * 1536 + hh * 64;
    #pragma unroll
    for (int nj = 0; nj < 2; ++nj)
      #pragma unroll
      for (int ks = 0; ks < 2; ++ks)
        qf[nj][ks] = *(const bf16x8*)(Qb + (size_t)(nj * 16 + c) * 1536 + ks * 32 + g * 8);
  }

  f32x4 accO[2][4] = {};                 // O[q=mi*16+g*4+j][d=dj*16+c]
  float mrow[2] = {-1e30f, -1e30f};
  float lrow[2] = {0.0f, 0.0f};

  // staging: thread t -> LDS linear row=t/8(+32p), chunk=t&7; global col pre-swizzled
  const int srow = tid >> 3;
  const int scol = ((tid & 7) ^ (srow & 7)) << 3;
  const unsigned short* gK = qkvb + (size_t)(b * 1024 + srow) * 1536 + 1024 + n * 64 + scol;
  const unsigned short* gV = vT + (size_t)((b * 4 + n) * 64 + srow) * 1024 + scol;
  unsigned short* lK = lsK + tid * 8;
  unsigned short* lV = lsV + tid * 8;

  const int ktmax = 2 * qt + 1;
  for (int kt = 0; kt <= ktmax; ++kt) {
    if (kt) __syncthreads();
    GLDS(gK + (size_t)kt * 64 * 1536, lK);
    GLDS(gK + (size_t)kt * 64 * 1536 + (size_t)32 * 1536, lK + 2048);
    GLDS(gV + (size_t)kt * 64, lV);
    GLDS(gV + (size_t)kt * 64 + (size_t)32 * 1024, lV + 2048);
    __syncthreads();
    if (kt > kdiag) continue;            // barrier counts stay uniform

    const bool dg = (kt == kdiag);
    const int kb = kt * 64;

    // S^T[k = mi*16+g*4+j][q = nj*16+c]
    f32x4 st[4][2] = {};
    #pragma unroll
    for (int ks = 0; ks < 2; ++ks) {
      const int col = (((ks * 4 + g) ^ (lane & 7)) << 3);
      bf16x8 kf[4];
      #pragma unroll
      for (int mi = 0; mi < 4; ++mi)
        kf[mi] = *(const bf16x8*)&lsK[(mi * 16 + c) * 64 + col];
      #pragma unroll
      for (int mi = 0; mi < 4; ++mi)
        #pragma unroll
        for (int nj = 0; nj < 2; ++nj)
          st[mi][nj] = __builtin_amdgcn_mfma_f32_16x16x32_bf16(kf[mi], qf[nj][ks], st[mi][nj], 0, 0, 0);
    }

    // online softmax per q (lane owns q = nj*16+c; reduce over g-lanes)
    float alv[2];
    #pragma unroll
    for (int nj = 0; nj < 2; ++nj) {
      const int qrow = q0w + nj * 16 + c;
      float mx = mrow[nj];
      #pragma unroll
      for (int mi = 0; mi < 4; ++mi)
        #pragma unroll
        for (int j = 0; j < 4; ++j) {
          float v = st[mi][nj][j] * 0.125f;
          if (dg && (kb + mi * 16 + g * 4 + j) > qrow) v = -1e30f;
          st[mi][nj][j] = v;
          mx = fmaxf(mx, v);
        }
      mx = fmaxf(mx, __shfl_xor(mx, 16));
      mx = fmaxf(mx, __shfl_xor(mx, 32));
      const float al = __expf(mrow[nj] - mx);
      float sum = 0.0f;
      #pragma unroll
      for (int mi = 0; mi < 4; ++mi) {
        bf16x4 pk;
        #pragma unroll
        for (int j = 0; j < 4; ++j) {
          const float e = __expf(st[mi][nj][j] - mx);
          sum += e;
          pk[j] = (short)f2b(e);
        }
        // P[q][k]: packed 4 k-contiguous; chunk XOR by q&7 (= c&7)
        *(bf16x4*)&Pw[(nj * 16 + c) * 64 + ((mi * 16 + g * 4) ^ ((c & 7) << 3))] = pk;
      }
      sum += __shfl_xor(sum, 16);
      sum += __shfl_xor(sum, 32);
      lrow[nj] = lrow[nj] * al + sum;
      mrow[nj] = mx;
      alv[nj] = al;
    }

    // rescale O: factor for row q=mi*16+g*4+j lives at lane g*4+j (alpha[mi])
    #pragma unroll
    for (int mi = 0; mi < 2; ++mi) {
      float aj[4];
      #pragma unroll
      for (int j = 0; j < 4; ++j) aj[j] = __shfl(alv[mi], g * 4 + j);
      #pragma unroll
      for (int dj = 0; dj < 4; ++dj)
        #pragma unroll
        for (int j = 0; j < 4; ++j) accO[mi][dj][j] *= aj[j];
    }

    // O += P·V
    #pragma unroll
    for (int ks = 0; ks < 2; ++ks) {
      const int col = (((ks * 4 + g) ^ (lane & 7)) << 3);
      bf16x8 pa[2], vf[4];
      #pragma unroll
      for (int mi = 0; mi < 2; ++mi)
        pa[mi] = *(const bf16x8*)&Pw[(mi * 16 + c) * 64 + col];
      #pragma unroll
      for (int dj = 0; dj < 4; ++dj)
        vf[dj] = *(const bf16x8*)&lsV[(dj * 16 + c) * 64 + col];
      #pragma unroll
      for (int mi = 0; mi < 2; ++mi)
        #pragma unroll
        for (int dj = 0; dj < 4; ++dj)
          accO[mi][dj] = __builtin_amdgcn_mfma_f32_16x16x32_bf16(pa[mi], vf[dj], accO[mi][dj], 0, 0, 0);
    }
  }

  // finalize: O /= l, write bf16
  float linv[2] = {1.0f / lrow[0], 1.0f / lrow[1]};
  unsigned short* obase = ob + (size_t)(b * 1024 + q0w) * 1024 + hh * 64;
  #pragma unroll
  for (int mi = 0; mi < 2; ++mi) {
    float lj[4];
    #pragma unroll
    for (int j = 0; j < 4; ++j) lj[j] = __shfl(linv[mi], g * 4 + j);
    #pragma unroll
    for (int dj = 0; dj < 4; ++dj)
      #pragma unroll
      for (int j = 0; j < 4; ++j)
        obase[(size_t)(mi * 16 + g * 4 + j) * 1024 + dj * 16 + c] = f2b(accO[mi][dj][j] * lj[j]);
  }
}

// ---------------- NT GEMM: C[M,N] = A[M,K] * Bt[N,K]^T, bf16 in, f32 acc ----------------
// BK=64, XOR chunk swizzle (store via pre-swizzled global col, read with same XOR).
// bx = M-tile (fastest) for B-panel L2 reuse; T1 XCD chunk swizzle.
template<int BM, int BN, bool BF16OUT, bool RELU, bool RESID>
__global__ LB void gemm_nt(const unsigned short* __restrict__ A, const unsigned short* __restrict__ Bt,
                           void* __restrict__ Cv, const float* __restrict__ Res,
                           int K, int lda, int ldb, int ldc) {
  constexpr int BK = 64;
  constexpr int WM = BM / 2, WN = BN / 2;
  constexpr int FM = WM / 16, FN = WN / 16;
  constexpr int PA = BM / 32, PB = BN / 32;
  int f = blockIdx.x + gridDim.x * blockIdx.y;
  const int nwg = gridDim.x * gridDim.y;
  if ((nwg & 7) == 0) f = (f & 7) * (nwg >> 3) + (f >> 3);
  const int bx = f % gridDim.x, by = f / gridDim.x;

  const int tid = threadIdx.x;
  const int lane = tid & 63, wid = tid >> 6;
  const int wr = wid >> 1, wc = wid & 1;
  const int m0 = bx * BM, n0 = by * BN;

  __shared__ unsigned short lsA[BM * BK];
  __shared__ unsigned short lsB[BN * BK];

  f32x4 acc[FM][FN] = {};

  const int srow = tid >> 3;
  const int scol = ((tid & 7) ^ (srow & 7)) << 3;
  const unsigned short* gA = A + (size_t)(m0 + srow) * lda + scol;
  const unsigned short* gB = Bt + (size_t)(n0 + srow) * ldb + scol;
  unsigned short* lA = lsA + tid * 8;
  unsigned short* lB = lsB + tid * 8;

  const int fr = lane & 15;
  const int j7 = lane & 7;
  const int g4 = lane >> 4;

  for (int k0 = 0; k0 < K; k0 += BK) {
    if (k0) __syncthreads();
    #pragma unroll
    for (int p = 0; p < PA; ++p)
      GLDS(gA + (size_t)(p * 32) * lda + k0, lA + p * 2048);
    #pragma unroll
    for (int p = 0; p < PB; ++p)
      GLDS(gB + (size_t)(p * 32) * ldb + k0, lB + p * 2048);
    __syncthreads();

    #pragma unroll
    for (int ks = 0; ks < 2; ++ks) {
      const int col = (((ks * 4 + g4) ^ j7) << 3);
      bf16x8 af[FM], bfv[FN];
      #pragma unroll
      for (int mi = 0; mi < FM; ++mi)
        af[mi] = *(const bf16x8*)&lsA[(wr * WM + mi * 16 + fr) * BK + col];
      #pragma unroll
      for (int nj = 0; nj < FN; ++nj)
        bfv[nj] = *(const bf16x8*)&lsB[(wc * WN + nj * 16 + fr) * BK + col];
      #pragma unroll
      for (int mi = 0; mi < FM; ++mi)
        #pragma unroll
        for (int nj = 0; nj < FN; ++nj)
          acc[mi][nj] = __builtin_amdgcn_mfma_f32_16x16x32_bf16(af[mi], bfv[nj], acc[mi][nj], 0, 0, 0);
    }
  }

  const int r0 = (lane >> 4) * 4, c0 = lane & 15;
  #pragma unroll
  for (int mi = 0; mi < FM; ++mi) {
    #pragma unroll
    for (int nj = 0; nj < FN; ++nj) {
      const int c = n0 + wc * WN + nj * 16 + c0;
      #pragma unroll
      for (int j = 0; j < 4; ++j) {
        const int r = m0 + wr * WM + mi * 16 + r0 + j;
        float v = acc[mi][nj][j];
        if (RELU) v = fmaxf(v, 0.0f);
        if (RESID) v += Res[(size_t)r * ldc + c];
        const size_t o = (size_t)r * ldc + c;
        if (BF16OUT) ((unsigned short*)Cv)[o] = f2b(v);
        else ((float*)Cv)[o] = v;
      }
    }
  }
}

extern "C" void kernel_launch(void* const* d_in, const int* in_sizes, int n_in,
                              void* d_out, int out_size, void* d_ws, size_t ws_size,
                              hipStream_t stream) {
  (void)in_sizes; (void)n_in; (void)out_size;
  const int*   idx      = (const int*)d_in[0];
  const float* tok_emb  = (const float*)d_in[1];
  const float* pos_emb  = (const float*)d_in[2];
  const float* q_proj   = (const float*)d_in[3];
  const float* kv_proj  = (const float*)d_in[4];
  const float* out_proj = (const float*)d_in[5];
  const float* fc_in    = (const float*)d_in[6];
  const float* fc_out   = (const float*)d_in[7];
  const float* scale    = (const float*)d_in[8];
  const float* out_scl  = (const float*)d_in[9];
  const float* lm_head  = (const float*)d_in[10];
  float* out = (float*)d_out;

  char* ws = (char*)d_ws;
  size_t off = 0;
  auto alloc = [&](size_t bytes) -> void* {
    void* p = ws + off;
    off += (bytes + 255) & ~(size_t)255;
    return p;
  };
  unsigned short* WqkvT = (unsigned short*)alloc((size_t)1536 * 1024 * 2);
  unsigned short* WoT   = (unsigned short*)alloc((size_t)1024 * 1024 * 2);
  unsigned short* F1T   = (unsigned short*)alloc((size_t)4096 * 1024 * 2);
  unsigned short* F2T   = (unsigned short*)alloc((size_t)1024 * 4096 * 2);
  float*  xbuf  = (float*)alloc((size_t)2048 * 1024 * 4);
  float*  hbuf  = (float*)alloc((size_t)2048 * 1024 * 4);
  float*  h2buf = (float*)alloc((size_t)2048 * 1024 * 4);
  unsigned short* actb  = (unsigned short*)alloc((size_t)2048 * 1024 * 2);
  unsigned short* qkvb  = (unsigned short*)alloc((size_t)2048 * 1536 * 2);
  unsigned short* vT    = (unsigned short*)alloc((size_t)2 * 256 * 1024 * 2);
  unsigned short* LmT   = (unsigned short*)alloc((size_t)32000 * 1024 * 2);
  unsigned short* ob    = (unsigned short*)alloc((size_t)2048 * 1024 * 2);
  unsigned short* m1    = (unsigned short*)alloc((size_t)2048 * 4096 * 2);
  if (off > ws_size) return;

  const dim3 thr(256);

  embed_kernel<<<dim3(2048), thr, 0, stream>>>(idx, tok_emb, pos_emb, xbuf);

  for (int l = 0; l < 8; ++l) {
    transpose_w<<<dim3(32, 32), thr, 0, stream>>>(q_proj + (size_t)l * 1024 * 1024, WqkvT, 1024, 0, 1024);
    transpose_w<<<dim3(8, 32), thr, 0, stream>>>(kv_proj + (size_t)l * 2 * 1024 * 256, WqkvT, 256, 1024, 1024);
    transpose_w<<<dim3(8, 32), thr, 0, stream>>>(kv_proj + (size_t)l * 2 * 1024 * 256 + 1024 * 256, WqkvT, 256, 1280, 1024);
    transpose_w<<<dim3(32, 32), thr, 0, stream>>>(out_proj + (size_t)l * 1024 * 1024, WoT, 1024, 0, 1024);
    transpose_w<<<dim3(128, 32), thr, 0, stream>>>(fc_in + (size_t)l * 1024 * 4096, F1T, 4096, 0, 1024);
    transpose_w<<<dim3(32, 128), thr, 0, stream>>>(fc_out + (size_t)l * 4096 * 1024, F2T, 1024, 0, 4096);

    const float* w1 = scale + (size_t)l * 2048;
    const float* w2 = w1 + 1024;

    ln_kernel<true><<<dim3(2048), thr, 0, stream>>>(xbuf, w1, hbuf, actb);
    // qkv = h @ Wqkv
    gemm_nt<128, 64, true, false, false><<<dim3(16, 24), thr, 0, stream>>>(
        actb, WqkvT, qkvb, nullptr, 1024, 1024, 1024, 1536);
    transpose_v<<<dim3(8, 32, 2), thr, 0, stream>>>(qkvb, vT);
    // fused attention -> ob
    attn_fused<<<dim3(8, 32), thr, 0, stream>>>(qkvb, vT, ob);
    // x = h + o @ Wo
    gemm_nt<128, 64, false, false, true><<<dim3(16, 16), thr, 0, stream>>>(
        ob, WoT, xbuf, hbuf, 1024, 1024, 1024, 1024);
    ln_kernel<true><<<dim3(2048), thr, 0, stream>>>(xbuf, w2, h2buf, actb);
    // m1 = relu(h2 @ fc1)
    gemm_nt<128, 128, true, true, false><<<dim3(16, 32), thr, 0, stream>>>(
        actb, F1T, m1, nullptr, 1024, 1024, 1024, 4096);
    // x = h2 + m1 @ fc2
    gemm_nt<128, 64, false, false, true><<<dim3(16, 16), thr, 0, stream>>>(
        m1, F2T, xbuf, h2buf, 4096, 4096, 4096, 1024);
  }

  transpose_w<<<dim3(1000, 32), thr, 0, stream>>>(lm_head, LmT, 32000, 0, 1024);
  ln_kernel<false><<<dim3(2048), thr, 0, stream>>>(xbuf, out_scl, nullptr, actb);
  gemm_nt<128, 128, false, false, false><<<dim3(16, 250), thr, 0, stream>>>(
      actb, LmT, out, nullptr, 1024, 1024, 1024, 32000);
}